// Round 4
// baseline (418.552 us; speedup 1.0000x reference)
//
#include <hip/hip_runtime.h>
#include <hip/hip_bf16.h>
#include <stdint.h>

typedef unsigned short u16;
typedef __attribute__((ext_vector_type(8)))  short    s16x8;
typedef __attribute__((ext_vector_type(8)))  __bf16   bf16x8;
typedef __attribute__((ext_vector_type(8)))  _Float16 f16x8;
typedef __attribute__((ext_vector_type(16))) float    f32x16;

#define B_DIM 16
#define N_SEQ 2048
#define D_DIM 256
#define M_TOT (B_DIM * N_SEQ)   // 32768
#define LOG2E 1.44269504088896f

static __device__ __forceinline__ u16 f2bf(float f) {
  union { float f; uint32_t u; } v; v.f = f;
  uint32_t u = v.u;
  return (u16)((u + 0x7FFFu + ((u >> 16) & 1u)) >> 16);   // RNE
}
static __device__ __forceinline__ float bf2f(u16 h) {
  union { uint32_t u; float f; } v; v.u = ((uint32_t)h) << 16;
  return v.f;
}

static __device__ __forceinline__ f32x16 MFMA32(s16x8 a, s16x8 b, f32x16 c) {
  return __builtin_amdgcn_mfma_f32_32x32x16_bf16(
      __builtin_bit_cast(bf16x8, a), __builtin_bit_cast(bf16x8, b), c, 0, 0, 0);
}
static __device__ __forceinline__ f32x16 MFMA16(f16x8 a, f16x8 b, f32x16 c) {
  return __builtin_amdgcn_mfma_f32_32x32x16_f16(a, b, c, 0, 0, 0);
}

// load 16 reg fragments (one 256-deep row, hi or lo) for lane half g
static __device__ __forceinline__ void load_frags(const u16* base, s16x8* f, int g) {
#pragma unroll
  for (int c = 0; c < 16; ++c) f[c] = *(const s16x8*)(base + c * 16 + g * 8);
}

// ---------------------------------------------------------------------------
// W split+transpose: WT[a][k] (a<256: W1*log2e, else W2), bf16 hi/lo.
// log2e folded into W1 so softmax can use raw exp2 (v_exp_f32).
// ---------------------------------------------------------------------------
__global__ void splitW_kernel(const float* __restrict__ W1, const float* __restrict__ W2,
                              u16* __restrict__ WTh, u16* __restrict__ WTl) {
  const int gid = blockIdx.x * 256 + threadIdx.x;   // 512 blocks -> 131072
  const int a = gid >> 8, k = gid & 255;
  const float v = (a < 256) ? W1[k * 256 + a] * LOG2E : W2[k * 256 + (a - 256)];
  const u16 h = f2bf(v);
  WTh[gid] = h;
  WTl[gid] = f2bf(v - bf2f(h));
}

// ---------------------------------------------------------------------------
// Projection: Qf = (x@W1+b1)*log2e, Kf = x@W2+b2, fp16 out (row-major [M][256]).
// GEMM in split-bf16 3-term (fp32-grade); only the OUTPUT is fp16.
// ---------------------------------------------------------------------------
__global__ __launch_bounds__(256, 2) void proj_kernel(
    const float* __restrict__ x,
    const u16* __restrict__ WTh, const u16* __restrict__ WTl,
    const float* __restrict__ b1, const float* __restrict__ b2,
    u16* __restrict__ Qf, u16* __restrict__ Kf)
{
  extern __shared__ char lds[];   // 2 x (16KB hi + 16KB lo)
  const int t = threadIdx.x, wv = t >> 6, ln = t & 63, lr = ln & 31, g = ln >> 5;
  const int ablk = blockIdx.x & 3;
  const int m0 = (blockIdx.x >> 2) * 256;
  const int aglob = ablk * 128 + wv * 32 + lr;

  s16x8 wfh[16], wfl[16];
  load_frags(WTh + (size_t)aglob * 256, wfh, g);
  load_frags(WTl + (size_t)aglob * 256, wfl, g);
  const float bias = (aglob < 256) ? b1[aglob] * LOG2E : b2[aglob - 256];
  u16* Of = (ablk < 2) ? Qf : Kf;
  const int acol = aglob & 255;

  const int srow = t >> 3;            // staging: row 0..31
  const int scol = (t & 7) * 32;      // 32 f32 per thread

  float4 v[8];
  // prologue: load rows m0, convert, write buf0
  {
    const float* src = x + (size_t)(m0 + srow) * 256 + scol;
#pragma unroll
    for (int j = 0; j < 8; ++j) v[j] = *(const float4*)(src + j * 4);
#pragma unroll
    for (int q8 = 0; q8 < 4; ++q8) {
      float ff[8] = {v[q8*2].x, v[q8*2].y, v[q8*2].z, v[q8*2].w,
                     v[q8*2+1].x, v[q8*2+1].y, v[q8*2+1].z, v[q8*2+1].w};
      s16x8 H, L;
#pragma unroll
      for (int e = 0; e < 8; ++e) {
        u16 h = f2bf(ff[e]); H[e] = (short)h; L[e] = (short)f2bf(ff[e] - bf2f(h));
      }
      const int swz = (((t & 7) * 4 + q8) ^ (srow & 7));
      *(s16x8*)(lds + srow * 512 + swz * 16) = H;
      *(s16x8*)(lds + 16384 + srow * 512 + swz * 16) = L;
    }
  }
  __syncthreads();
  int p = 0;
  for (int it = 0; it < 8; ++it) {
    if (it + 1 < 8) {   // issue next-tile global loads early (overlap MFMA)
      const float* src = x + (size_t)(m0 + (it + 1) * 32 + srow) * 256 + scol;
#pragma unroll
      for (int j = 0; j < 8; ++j) v[j] = *(const float4*)(src + j * 4);
    }
    const char* bh = lds + p * 32768;
    const char* bl = bh + 16384;
    f32x16 S = {};
#pragma unroll
    for (int cc = 0; cc < 16; ++cc) {
      const int sl = ((cc * 2 + g) ^ (lr & 7)) * 16;
      s16x8 ah = *(const s16x8*)(bh + lr * 512 + sl);
      s16x8 al = *(const s16x8*)(bl + lr * 512 + sl);
      S = MFMA32(ah, wfh[cc], S);
      S = MFMA32(ah, wfl[cc], S);
      S = MFMA32(al, wfh[cc], S);
    }
    // write outputs: 32 m-rows x wave's 32 a-cols (coalesced 64B rows)
#pragma unroll
    for (int i = 0; i < 16; ++i) {
      const int mrow = m0 + it * 32 + (i & 3) + 8 * (i >> 2) + 4 * g;
      const float val = S[i] + bias;
      Of[(size_t)mrow * 256 + acol] = __builtin_bit_cast(u16, (_Float16)val);
    }
    if (it + 1 < 8) {   // convert + write next tile into other buffer
      char* basep = lds + (p ^ 1) * 32768;
#pragma unroll
      for (int q8 = 0; q8 < 4; ++q8) {
        float ff[8] = {v[q8*2].x, v[q8*2].y, v[q8*2].z, v[q8*2].w,
                       v[q8*2+1].x, v[q8*2+1].y, v[q8*2+1].z, v[q8*2+1].w};
        s16x8 H, L;
#pragma unroll
        for (int e = 0; e < 8; ++e) {
          u16 h = f2bf(ff[e]); H[e] = (short)h; L[e] = (short)f2bf(ff[e] - bf2f(h));
        }
        const int swz = (((t & 7) * 4 + q8) ^ (srow & 7));
        *(s16x8*)(basep + srow * 512 + swz * 16) = H;
        *(s16x8*)(basep + 16384 + srow * 512 + swz * 16) = L;
      }
    }
    __syncthreads();
    p ^= 1;
  }
}

// block-index swizzle: 16 blocks sharing one (batch,half) K/Q working set land
// on the SAME XCD (physical bid%8 = XCD under round-robin dispatch).
// bid = r + 8*(sub + 16*gh);  grp = 8*gh + r in [0,32);  sub in [0,16).
#define SWZ_DECODE(bid, grp, sub)                       \
  const int grp = (((bid) >> 7) << 3) | ((bid) & 7);    \
  const int sub = ((bid) >> 3) & 15;

// per-tile online-softmax update (pass1). SA/SB: dual accumulators (even/odd cc).
#define P1_UPDATE(SA, SB)                                                   \
  {                                                                         \
    float mx = -1e30f;                                                      \
    _Pragma("unroll")                                                       \
    for (int i = 0; i < 16; ++i) {                                          \
      float s = SA[i] + SB[i]; SA[i] = s; mx = fmaxf(mx, s);                \
    }                                                                       \
    mx = fmaxf(mx, __shfl_xor(mx, 32));                                     \
    const float mn = fmaxf(m_run, mx);                                      \
    float rs = 0.f;                                                         \
    _Pragma("unroll")                                                       \
    for (int i = 0; i < 16; ++i) rs += exp2f(SA[i] - mn);                   \
    rs += __shfl_xor(rs, 32);                                               \
    l_run = l_run * exp2f(m_run - mn) + rs;                                 \
    m_run = mn;                                                             \
  }

// ---------------------------------------------------------------------------
// Pass 1: per-query (m, l) over one k-half. fp16 single MFMA, S' in log2 units.
// No LDS, no barriers: K fragments streamed from L2 into regs, double-buffered.
// Q (32 q/wave) persistent in regs.  Lane holds 1 q-col x 16 key-rows.
// ---------------------------------------------------------------------------
__global__ __launch_bounds__(256, 2) void pass1_kernel(
    const u16* __restrict__ Qf, const u16* __restrict__ Kf,
    float* __restrict__ mpart, float* __restrict__ lpart)
{
  SWZ_DECODE(blockIdx.x, grp, sub);
  const int b = grp >> 1, khalf = grp & 1, qblk = sub;
  const int t = threadIdx.x, wv = t >> 6, ln = t & 63, lr = ln & 31, gg = ln >> 5;

  const int qrow = b * 2048 + qblk * 128 + wv * 32 + lr;
  f16x8 qf[16];
  {
    const u16* qb = Qf + (size_t)qrow * 256 + gg * 8;
#pragma unroll
    for (int c = 0; c < 16; ++c) qf[c] = *(const f16x8*)(qb + c * 16);
  }
  const u16* kbase = Kf + ((size_t)(b * 2048 + khalf * 1024) + lr) * 256 + gg * 8;

  f16x8 ka[16], kb[16];
#pragma unroll
  for (int c = 0; c < 16; ++c) ka[c] = *(const f16x8*)(kbase + c * 16);

  float m_run = -1e30f, l_run = 0.f;

  for (int it = 0; it < 32; it += 2) {
    const u16* p1 = kbase + (size_t)(it + 1) * 32 * 256;
#pragma unroll
    for (int c = 0; c < 16; ++c) kb[c] = *(const f16x8*)(p1 + c * 16);
    f32x16 S0 = {}, S1 = {};
#pragma unroll
    for (int c = 0; c < 8; ++c) {
      S0 = MFMA16(ka[2 * c],     qf[2 * c],     S0);
      S1 = MFMA16(ka[2 * c + 1], qf[2 * c + 1], S1);
    }
    P1_UPDATE(S0, S1);
    if (it + 2 < 32) {
      const u16* p2 = kbase + (size_t)(it + 2) * 32 * 256;
#pragma unroll
      for (int c = 0; c < 16; ++c) ka[c] = *(const f16x8*)(p2 + c * 16);
    }
    f32x16 T0 = {}, T1 = {};
#pragma unroll
    for (int c = 0; c < 8; ++c) {
      T0 = MFMA16(kb[2 * c],     qf[2 * c],     T0);
      T1 = MFMA16(kb[2 * c + 1], qf[2 * c + 1], T1);
    }
    P1_UPDATE(T0, T1);
  }
  if (ln < 32) {
    const int q = b * 2048 + qblk * 128 + wv * 32 + ln;
    mpart[khalf * M_TOT + q] = m_run;
    lpart[khalf * M_TOT + q] = l_run;
  }
}

__global__ void merge_kernel(const float* __restrict__ mpart, const float* __restrict__ lpart,
                             float* __restrict__ mfin, float* __restrict__ linv) {
  const int q = blockIdx.x * 256 + threadIdx.x;
  const float m0 = mpart[q], m1 = mpart[M_TOT + q];
  const float l0 = lpart[q], l1 = lpart[M_TOT + q];
  const float m = fmaxf(m0, m1);
  const float l = l0 * exp2f(m0 - m) + l1 * exp2f(m1 - m);
  mfin[q] = m;
  linv[q] = 1.f / l;
}

// ---------------------------------------------------------------------------
// Pass 2: c_k = sum_q exp2(S'-m_q)*invl_q. K (32 keys/wave) persistent in regs,
// Q streamed from L2. Same operands+order as pass1 -> bitwise-identical S'.
// ---------------------------------------------------------------------------
__global__ __launch_bounds__(256, 2) void pass2_kernel(
    const u16* __restrict__ Qf, const u16* __restrict__ Kf,
    const float* __restrict__ mfin, const float* __restrict__ linv,
    float* __restrict__ cvec)
{
  SWZ_DECODE(blockIdx.x, grp, sub);
  const int b = grp >> 1, qhalf = grp & 1, kblk = sub;
  const int t = threadIdx.x, wv = t >> 6, ln = t & 63, lr = ln & 31, gg = ln >> 5;

  const int krow = b * 2048 + kblk * 128 + wv * 32 + lr;
  f16x8 kf[16];
  {
    const u16* kb = Kf + (size_t)krow * 256 + gg * 8;
#pragma unroll
    for (int c = 0; c < 16; ++c) kf[c] = *(const f16x8*)(kb + c * 16);
  }
  const int q0 = b * 2048 + qhalf * 1024;
  const u16* qbase = Qf + ((size_t)q0 + lr) * 256 + gg * 8;

  float ck[16];
#pragma unroll
  for (int i = 0; i < 16; ++i) ck[i] = 0.f;

  for (int it = 0; it < 32; ++it) {
    const u16* p = qbase + (size_t)it * 32 * 256;
    f16x8 qa[16];
#pragma unroll
    for (int c = 0; c < 16; ++c) qa[c] = *(const f16x8*)(p + c * 16);
    const int qi = q0 + it * 32 + lr;
    const float mq = mfin[qi];
    const float il = linv[qi];
    f32x16 S0 = {}, S1 = {};
#pragma unroll
    for (int c = 0; c < 8; ++c) {
      S0 = MFMA16(kf[2 * c],     qa[2 * c],     S0);
      S1 = MFMA16(kf[2 * c + 1], qa[2 * c + 1], S1);
    }
#pragma unroll
    for (int i = 0; i < 16; ++i) ck[i] += exp2f((S0[i] + S1[i]) - mq) * il;
  }
  // reduce over the 32 q-columns (lanes within each 32-half hold distinct q)
#pragma unroll
  for (int i = 0; i < 16; ++i) {
#pragma unroll
    for (int d = 1; d <= 16; d <<= 1) ck[i] += __shfl_xor(ck[i], d);
  }
  if (lr == 0) {
#pragma unroll
    for (int i = 0; i < 16; ++i) {
      const int klocal = (i & 3) + 8 * (i >> 2) + 4 * gg;
      atomicAdd(&cvec[b * 2048 + kblk * 128 + wv * 32 + klocal], ck[i]);
    }
  }
}

// y[b][d] = sum_k c_k x[b,k,d]; sumc[b] = sum_k c_k
__global__ void reducey_kernel(const float* __restrict__ x, const float* __restrict__ cvec,
                               float* __restrict__ yv, float* __restrict__ sumc) {
  const int b = blockIdx.x >> 4, kc = blockIdx.x & 15, tid = threadIdx.x;
  const float* xb = x + ((size_t)b * 2048 + kc * 128) * 256;
  const float* cb = cvec + b * 2048 + kc * 128;
  float a0 = 0.f, a1 = 0.f, a2 = 0.f, a3 = 0.f;
  for (int k = 0; k < 128; k += 4) {
    a0 = fmaf(cb[k],     xb[(size_t)k * 256 + tid],         a0);
    a1 = fmaf(cb[k + 1], xb[(size_t)(k + 1) * 256 + tid],   a1);
    a2 = fmaf(cb[k + 2], xb[(size_t)(k + 2) * 256 + tid],   a2);
    a3 = fmaf(cb[k + 3], xb[(size_t)(k + 3) * 256 + tid],   a3);
  }
  atomicAdd(&yv[b * 256 + tid], (a0 + a1) + (a2 + a3));
  if (tid == 0) {
    float s = 0.f;
    for (int k = 0; k < 128; ++k) s += cb[k];
    atomicAdd(&sumc[b], s);
  }
}

// out[b][a] = sum_d y[b,d] W3[d,a] + sumc[b]*b3[a]
__global__ void final_kernel(const float* __restrict__ yv, const float* __restrict__ sumc,
                             const float* __restrict__ W3, const float* __restrict__ b3,
                             float* __restrict__ out) {
  __shared__ float ys[256];
  const int b = blockIdx.x, a = threadIdx.x;
  ys[a] = yv[b * 256 + a];
  __syncthreads();
  float acc = sumc[b] * b3[a];
#pragma unroll 4
  for (int d = 0; d < 256; ++d) acc = fmaf(ys[d], W3[d * 256 + a], acc);
  out[b * 256 + a] = acc;
}

// ---------------------------------------------------------------------------
extern "C" void kernel_launch(void* const* d_in, const int* in_sizes, int n_in,
                              void* d_out, int out_size, void* d_ws, size_t ws_size,
                              hipStream_t stream) {
  const float* x  = (const float*)d_in[0];
  const float* W1 = (const float*)d_in[1];
  const float* b1 = (const float*)d_in[2];
  const float* W2 = (const float*)d_in[3];
  const float* b2 = (const float*)d_in[4];
  const float* W3 = (const float*)d_in[5];
  const float* b3 = (const float*)d_in[6];
  float* out = (float*)d_out;

  char* ws = (char*)d_ws;
  const size_t SZ_WT = 512u * 256u * 2u;          // 262144 B
  const size_t SZ_QK = (size_t)M_TOT * 256u * 2u; // 16 MB
  u16* WTh = (u16*)(ws);                 ws += SZ_WT;
  u16* WTl = (u16*)(ws);                 ws += SZ_WT;
  u16* Qf  = (u16*)(ws);                 ws += SZ_QK;
  u16* Kf  = (u16*)(ws);                 ws += SZ_QK;
  float* mpart = (float*)(ws);           ws += 2u * M_TOT * 4u;
  float* lpart = (float*)(ws);           ws += 2u * M_TOT * 4u;
  float* mfin  = (float*)(ws);           ws += (size_t)M_TOT * 4u;
  float* linv  = (float*)(ws);           ws += (size_t)M_TOT * 4u;
  float* cvec  = (float*)(ws);           ws += (size_t)M_TOT * 4u;
  float* yv    = (float*)(ws);           ws += 4096u * 4u;
  float* sumc  = (float*)(ws);           ws += 64u;

  // zero the accumulated buffers (cvec | yv | sumc are contiguous)
  hipMemsetAsync(cvec, 0, (size_t)M_TOT * 4u + 4096u * 4u + 64u, stream);

  const int LDSB = 65536;
  hipFuncSetAttribute((const void*)proj_kernel,
                      hipFuncAttributeMaxDynamicSharedMemorySize, LDSB);

  splitW_kernel<<<dim3(512), dim3(256), 0, stream>>>(W1, W2, WTh, WTl);
  proj_kernel<<<dim3(512), dim3(256), LDSB, stream>>>(x, WTh, WTl, b1, b2, Qf, Kf);
  pass1_kernel<<<dim3(512), dim3(256), 0, stream>>>(Qf, Kf, mpart, lpart);
  merge_kernel<<<dim3(128), dim3(256), 0, stream>>>(mpart, lpart, mfin, linv);
  pass2_kernel<<<dim3(512), dim3(256), 0, stream>>>(Qf, Kf, mfin, linv, cvec);
  reducey_kernel<<<dim3(256), dim3(256), 0, stream>>>(x, cvec, yv, sumc);
  final_kernel<<<dim3(16), dim3(256), 0, stream>>>(yv, sumc, W3, b3, out);
}

// Round 5
// 259.414 us; speedup vs baseline: 1.6135x; 1.6135x over previous
//
#include <hip/hip_runtime.h>
#include <hip/hip_bf16.h>
#include <stdint.h>

typedef unsigned short u16;
typedef __attribute__((ext_vector_type(8)))  short    s16x8;
typedef __attribute__((ext_vector_type(8)))  __bf16   bf16x8;
typedef __attribute__((ext_vector_type(8)))  _Float16 f16x8;
typedef __attribute__((ext_vector_type(16))) float    f32x16;

#define B_DIM 16
#define N_SEQ 2048
#define D_DIM 256
#define M_TOT (B_DIM * N_SEQ)   // 32768
#define LOG2E 1.44269504088896f

static __device__ __forceinline__ u16 f2bf(float f) {
  union { float f; uint32_t u; } v; v.f = f;
  uint32_t u = v.u;
  return (u16)((u + 0x7FFFu + ((u >> 16) & 1u)) >> 16);   // RNE
}
static __device__ __forceinline__ float bf2f(u16 h) {
  union { uint32_t u; float f; } v; v.u = ((uint32_t)h) << 16;
  return v.f;
}

static __device__ __forceinline__ f32x16 MFMA32(s16x8 a, s16x8 b, f32x16 c) {
  return __builtin_amdgcn_mfma_f32_32x32x16_bf16(
      __builtin_bit_cast(bf16x8, a), __builtin_bit_cast(bf16x8, b), c, 0, 0, 0);
}
static __device__ __forceinline__ f32x16 MFMA16(f16x8 a, f16x8 b, f32x16 c) {
  return __builtin_amdgcn_mfma_f32_32x32x16_f16(a, b, c, 0, 0, 0);
}

static __device__ __forceinline__ void load_frags(const u16* base, s16x8* f, int g) {
#pragma unroll
  for (int c = 0; c < 16; ++c) f[c] = *(const s16x8*)(base + c * 16 + g * 8);
}

// Stage a 32-row x 512-B fp16 tile into LDS with involution swizzle
// (LDS(row, sl) holds global (row, sl ^ (row&7))). gload_lds dest is linear
// (uniform base + lane*16); the SOURCE address carries the swizzle.
static __device__ __forceinline__ void stage_f16(
    const u16* __restrict__ src, char* ldsbuf, int row0, int t)
{
#pragma unroll
  for (int jj = 0; jj < 2; ++jj) {
    const int row = (t >> 5) + jj * 16;          // 0..31
    const int sl  = (t & 31) ^ (row & 7);        // swizzled 16B-slot
    const char* g = (const char*)src + ((size_t)(row0 + row) * 512 + (size_t)sl * 16);
    __builtin_amdgcn_global_load_lds(
        (const __attribute__((address_space(1))) uint32_t*)g,
        (__attribute__((address_space(3))) uint32_t*)(ldsbuf + t * 16 + jj * 8192),
        16, 0, 0);
  }
}

// online-softmax update over one 32-key tile; lane holds 16 keys (its gg half),
// partner half merged via shfl_xor(32). Both halves end with identical m/l.
static __device__ __forceinline__ void sm_update(const f32x16& S, float& m_run, float& l_run) {
  float mx = S[0];
#pragma unroll
  for (int i = 1; i < 16; ++i) mx = fmaxf(mx, S[i]);
  mx = fmaxf(mx, __shfl_xor(mx, 32));
  const float mn = fmaxf(m_run, mx);
  float rs = 0.f;
#pragma unroll
  for (int i = 0; i < 16; ++i) rs += exp2f(S[i] - mn);
  rs += __shfl_xor(rs, 32);
  l_run = l_run * exp2f(m_run - mn) + rs;
  m_run = mn;
}

// block-id swizzle: 4 sibling blocks (same working-set quarter) -> same XCD.
// p = (s&7) + 8*(j + 4*(s>>3));  s = sibling group (b*4+quarter), j = member.
#define SWZ_DECODE(P, S_, J_)                                  \
  const int xcd_ = (P) & 7, r_ = (P) >> 3;                     \
  const int J_ = r_ & 3;                                       \
  const int S_ = ((r_ >> 2) << 3) | xcd_;

// ---------------------------------------------------------------------------
// W split+transpose: WT[a][k] (a<256: W1*log2e, else W2), bf16 hi/lo.
// ---------------------------------------------------------------------------
__global__ void splitW_kernel(const float* __restrict__ W1, const float* __restrict__ W2,
                              u16* __restrict__ WTh, u16* __restrict__ WTl) {
  const int gid = blockIdx.x * 256 + threadIdx.x;
  const int a = gid >> 8, k = gid & 255;
  const float v = (a < 256) ? W1[k * 256 + a] * LOG2E : W2[k * 256 + (a - 256)];
  const u16 h = f2bf(v);
  WTh[gid] = h;
  WTl[gid] = f2bf(v - bf2f(h));
}

// ---------------------------------------------------------------------------
// Projection: Qf = (x@W1+b1)*log2e, Kf = x@W2+b2, fp16 out (row-major [M][256]).
// Split-bf16 3-term GEMM (fp32-grade); only the OUTPUT is fp16.
// ---------------------------------------------------------------------------
__global__ __launch_bounds__(256, 2) void proj_kernel(
    const float* __restrict__ x,
    const u16* __restrict__ WTh, const u16* __restrict__ WTl,
    const float* __restrict__ b1, const float* __restrict__ b2,
    u16* __restrict__ Qf, u16* __restrict__ Kf)
{
  extern __shared__ char lds[];   // 2 x (16KB hi + 16KB lo)
  const int t = threadIdx.x, wv = t >> 6, ln = t & 63, lr = ln & 31, g = ln >> 5;
  const int ablk = blockIdx.x & 3;
  const int m0 = (blockIdx.x >> 2) * 256;
  const int aglob = ablk * 128 + wv * 32 + lr;

  s16x8 wfh[16], wfl[16];
  load_frags(WTh + (size_t)aglob * 256, wfh, g);
  load_frags(WTl + (size_t)aglob * 256, wfl, g);
  const float bias = (aglob < 256) ? b1[aglob] * LOG2E : b2[aglob - 256];
  u16* Of = (ablk < 2) ? Qf : Kf;
  const int acol = aglob & 255;

  const int srow = t >> 3;
  const int scol = (t & 7) * 32;

  float4 v[8];
  {
    const float* src = x + (size_t)(m0 + srow) * 256 + scol;
#pragma unroll
    for (int j = 0; j < 8; ++j) v[j] = *(const float4*)(src + j * 4);
#pragma unroll
    for (int q8 = 0; q8 < 4; ++q8) {
      float ff[8] = {v[q8*2].x, v[q8*2].y, v[q8*2].z, v[q8*2].w,
                     v[q8*2+1].x, v[q8*2+1].y, v[q8*2+1].z, v[q8*2+1].w};
      s16x8 H, L;
#pragma unroll
      for (int e = 0; e < 8; ++e) {
        u16 h = f2bf(ff[e]); H[e] = (short)h; L[e] = (short)f2bf(ff[e] - bf2f(h));
      }
      const int swz = (((t & 7) * 4 + q8) ^ (srow & 7));
      *(s16x8*)(lds + srow * 512 + swz * 16) = H;
      *(s16x8*)(lds + 16384 + srow * 512 + swz * 16) = L;
    }
  }
  __syncthreads();
  int p = 0;
  for (int it = 0; it < 8; ++it) {
    if (it + 1 < 8) {
      const float* src = x + (size_t)(m0 + (it + 1) * 32 + srow) * 256 + scol;
#pragma unroll
      for (int j = 0; j < 8; ++j) v[j] = *(const float4*)(src + j * 4);
    }
    const char* bh = lds + p * 32768;
    const char* bl = bh + 16384;
    f32x16 S = {};
#pragma unroll
    for (int cc = 0; cc < 16; ++cc) {
      const int sl = ((cc * 2 + g) ^ (lr & 7)) * 16;
      s16x8 ah = *(const s16x8*)(bh + lr * 512 + sl);
      s16x8 al = *(const s16x8*)(bl + lr * 512 + sl);
      S = MFMA32(ah, wfh[cc], S);
      S = MFMA32(ah, wfl[cc], S);
      S = MFMA32(al, wfh[cc], S);
    }
#pragma unroll
    for (int i = 0; i < 16; ++i) {
      const int mrow = m0 + it * 32 + (i & 3) + 8 * (i >> 2) + 4 * g;
      const float val = S[i] + bias;
      Of[(size_t)mrow * 256 + acol] = __builtin_bit_cast(u16, (_Float16)val);
    }
    if (it + 1 < 8) {
      char* basep = lds + (p ^ 1) * 32768;
#pragma unroll
      for (int q8 = 0; q8 < 4; ++q8) {
        float ff[8] = {v[q8*2].x, v[q8*2].y, v[q8*2].z, v[q8*2].w,
                       v[q8*2+1].x, v[q8*2+1].y, v[q8*2+1].z, v[q8*2+1].w};
        s16x8 H, L;
#pragma unroll
        for (int e = 0; e < 8; ++e) {
          u16 h = f2bf(ff[e]); H[e] = (short)h; L[e] = (short)f2bf(ff[e] - bf2f(h));
        }
        const int swz = (((t & 7) * 4 + q8) ^ (srow & 7));
        *(s16x8*)(basep + srow * 512 + swz * 16) = H;
        *(s16x8*)(basep + 16384 + srow * 512 + swz * 16) = L;
      }
    }
    __syncthreads();
    p ^= 1;
  }
}

// ---------------------------------------------------------------------------
// Pass 1: (m, l) per query over one key-quarter (512 keys).
// 8 waves x 64 q (2 groups of 32, in regs); K staged through swizzled LDS
// (coalesced gload_lds), each K-fragment feeds 2 MFMA.
// ---------------------------------------------------------------------------
__global__ __launch_bounds__(512, 2) void pass1_kernel(
    const u16* __restrict__ Qf, const u16* __restrict__ Kf,
    float* __restrict__ mpart, float* __restrict__ lpart)
{
  extern __shared__ char lds[];   // 2 x 16 KB
  SWZ_DECODE(blockIdx.x, s, j);
  const int b = s >> 2, kq = s & 3;               // batch, key-quarter
  const int t = threadIdx.x, wv = t >> 6, ln = t & 63, lr = ln & 31, gg = ln >> 5;

  const int q0 = b * 2048 + j * 512 + wv * 64;    // this wave's 64 queries
  f16x8 qf0[16], qf1[16];
  {
    const u16* qb0 = Qf + (size_t)(q0 + lr) * 256 + gg * 8;
    const u16* qb1 = qb0 + 32 * 256;
#pragma unroll
    for (int c = 0; c < 16; ++c) {
      qf0[c] = *(const f16x8*)(qb0 + c * 16);
      qf1[c] = *(const f16x8*)(qb1 + c * 16);
    }
  }
  const int k0 = b * 2048 + kq * 512;

  stage_f16(Kf, lds, k0, t);
  __syncthreads();
  float m0 = -1e30f, l0 = 0.f, m1 = -1e30f, l1 = 0.f;
  int pp = 0;
  for (int it = 0; it < 16; ++it) {
    if (it + 1 < 16) stage_f16(Kf, lds + (pp ^ 1) * 16384, k0 + (it + 1) * 32, t);
    const char* bh = lds + pp * 16384;
    f32x16 S0 = {}, S1 = {};
#pragma unroll
    for (int c = 0; c < 16; ++c) {
      const int sl = ((c * 2 + gg) ^ (lr & 7)) * 16;
      const f16x8 a = *(const f16x8*)(bh + lr * 512 + sl);
      S0 = MFMA16(a, qf0[c], S0);
      S1 = MFMA16(a, qf1[c], S1);
    }
    sm_update(S0, m0, l0);
    sm_update(S1, m1, l1);
    __syncthreads();
    pp ^= 1;
  }
  if (ln < 32) {
    mpart[kq * M_TOT + q0 + ln]      = m0;
    lpart[kq * M_TOT + q0 + ln]      = l0;
    mpart[kq * M_TOT + q0 + 32 + ln] = m1;
    lpart[kq * M_TOT + q0 + 32 + ln] = l1;
  }
}

__global__ void merge_kernel(const float* __restrict__ mpart, const float* __restrict__ lpart,
                             float* __restrict__ mfin, float* __restrict__ linv) {
  const int q = blockIdx.x * 256 + threadIdx.x;
  float m = mpart[q];
#pragma unroll
  for (int i = 1; i < 4; ++i) m = fmaxf(m, mpart[i * M_TOT + q]);
  float l = 0.f;
#pragma unroll
  for (int i = 0; i < 4; ++i) l += lpart[i * M_TOT + q] * exp2f(mpart[i * M_TOT + q] - m);
  mfin[q] = m;
  linv[q] = 1.f / l;
}

// ---------------------------------------------------------------------------
// Pass 2: c_k = sum_q exp2(S'-m_q)*invl_q over one query-quarter.
// 8 waves x 64 keys (in regs); Q staged through swizzled LDS.
// Same operand values + same single-chain MFMA order as pass1 -> identical S'.
// ---------------------------------------------------------------------------
__global__ __launch_bounds__(512, 2) void pass2_kernel(
    const u16* __restrict__ Qf, const u16* __restrict__ Kf,
    const float* __restrict__ mfin, const float* __restrict__ linv,
    float* __restrict__ cvec)
{
  extern __shared__ char lds[];   // 2 x 16 KB
  SWZ_DECODE(blockIdx.x, s, j);
  const int b = s >> 2, qq = s & 3;               // batch, query-quarter
  const int t = threadIdx.x, wv = t >> 6, ln = t & 63, lr = ln & 31, gg = ln >> 5;

  const int k0 = b * 2048 + j * 512 + wv * 64;    // this wave's 64 keys
  f16x8 kf0[16], kf1[16];
  {
    const u16* kb0 = Kf + (size_t)(k0 + lr) * 256 + gg * 8;
    const u16* kb1 = kb0 + 32 * 256;
#pragma unroll
    for (int c = 0; c < 16; ++c) {
      kf0[c] = *(const f16x8*)(kb0 + c * 16);
      kf1[c] = *(const f16x8*)(kb1 + c * 16);
    }
  }
  const int q0 = b * 2048 + qq * 512;

  float ck0[16], ck1[16];
#pragma unroll
  for (int i = 0; i < 16; ++i) { ck0[i] = 0.f; ck1[i] = 0.f; }

  stage_f16(Qf, lds, q0, t);
  __syncthreads();
  int pp = 0;
  for (int it = 0; it < 16; ++it) {
    if (it + 1 < 16) stage_f16(Qf, lds + (pp ^ 1) * 16384, q0 + (it + 1) * 32, t);
    const char* bh = lds + pp * 16384;
    f32x16 S0 = {}, S1 = {};
#pragma unroll
    for (int c = 0; c < 16; ++c) {
      const int sl = ((c * 2 + gg) ^ (lr & 7)) * 16;
      const f16x8 qa = *(const f16x8*)(bh + lr * 512 + sl);
      S0 = MFMA16(kf0[c], qa, S0);
      S1 = MFMA16(kf1[c], qa, S1);
    }
    const int qi = q0 + it * 32 + lr;
    const float mq = mfin[qi];
    const float il = linv[qi];
#pragma unroll
    for (int i = 0; i < 16; ++i) {
      ck0[i] += exp2f(S0[i] - mq) * il;
      ck1[i] += exp2f(S1[i] - mq) * il;
    }
    __syncthreads();
    pp ^= 1;
  }
  // reduce over the 32 q-columns (lanes within each gg half hold distinct q)
#pragma unroll
  for (int i = 0; i < 16; ++i) {
#pragma unroll
    for (int d = 1; d <= 16; d <<= 1) {
      ck0[i] += __shfl_xor(ck0[i], d);
      ck1[i] += __shfl_xor(ck1[i], d);
    }
  }
  if (lr == 0) {
#pragma unroll
    for (int i = 0; i < 16; ++i) {
      const int klocal = (i & 3) + 8 * (i >> 2) + 4 * gg;
      atomicAdd(&cvec[k0 + klocal],      ck0[i]);
      atomicAdd(&cvec[k0 + 32 + klocal], ck1[i]);
    }
  }
}

// y[b][d] = sum_k c_k x[b,k,d]; sumc[b] = sum_k c_k
__global__ void reducey_kernel(const float* __restrict__ x, const float* __restrict__ cvec,
                               float* __restrict__ yv, float* __restrict__ sumc) {
  const int b = blockIdx.x >> 4, kc = blockIdx.x & 15, tid = threadIdx.x;
  const float* xb = x + ((size_t)b * 2048 + kc * 128) * 256;
  const float* cb = cvec + b * 2048 + kc * 128;
  float a0 = 0.f, a1 = 0.f, a2 = 0.f, a3 = 0.f;
  for (int k = 0; k < 128; k += 4) {
    a0 = fmaf(cb[k],     xb[(size_t)k * 256 + tid],       a0);
    a1 = fmaf(cb[k + 1], xb[(size_t)(k + 1) * 256 + tid], a1);
    a2 = fmaf(cb[k + 2], xb[(size_t)(k + 2) * 256 + tid], a2);
    a3 = fmaf(cb[k + 3], xb[(size_t)(k + 3) * 256 + tid], a3);
  }
  atomicAdd(&yv[b * 256 + tid], (a0 + a1) + (a2 + a3));
  if (tid == 0) {
    float s = 0.f;
    for (int k = 0; k < 128; ++k) s += cb[k];
    atomicAdd(&sumc[b], s);
  }
}

// out[b][a] = sum_d y[b,d] W3[d,a] + sumc[b]*b3[a]
__global__ void final_kernel(const float* __restrict__ yv, const float* __restrict__ sumc,
                             const float* __restrict__ W3, const float* __restrict__ b3,
                             float* __restrict__ out) {
  __shared__ float ys[256];
  const int b = blockIdx.x, a = threadIdx.x;
  ys[a] = yv[b * 256 + a];
  __syncthreads();
  float acc = sumc[b] * b3[a];
#pragma unroll 4
  for (int d = 0; d < 256; ++d) acc = fmaf(ys[d], W3[d * 256 + a], acc);
  out[b * 256 + a] = acc;
}

// ---------------------------------------------------------------------------
extern "C" void kernel_launch(void* const* d_in, const int* in_sizes, int n_in,
                              void* d_out, int out_size, void* d_ws, size_t ws_size,
                              hipStream_t stream) {
  const float* x  = (const float*)d_in[0];
  const float* W1 = (const float*)d_in[1];
  const float* b1 = (const float*)d_in[2];
  const float* W2 = (const float*)d_in[3];
  const float* b2 = (const float*)d_in[4];
  const float* W3 = (const float*)d_in[5];
  const float* b3 = (const float*)d_in[6];
  float* out = (float*)d_out;

  char* ws = (char*)d_ws;
  const size_t SZ_WT = 512u * 256u * 2u;          // 262144 B
  const size_t SZ_QK = (size_t)M_TOT * 256u * 2u; // 16 MB
  u16* WTh = (u16*)(ws);                 ws += SZ_WT;
  u16* WTl = (u16*)(ws);                 ws += SZ_WT;
  u16* Qf  = (u16*)(ws);                 ws += SZ_QK;
  u16* Kf  = (u16*)(ws);                 ws += SZ_QK;
  float* mpart = (float*)(ws);           ws += 4u * M_TOT * 4u;
  float* lpart = (float*)(ws);           ws += 4u * M_TOT * 4u;
  float* mfin  = (float*)(ws);           ws += (size_t)M_TOT * 4u;
  float* linv  = (float*)(ws);           ws += (size_t)M_TOT * 4u;
  float* cvec  = (float*)(ws);           ws += (size_t)M_TOT * 4u;
  float* yv    = (float*)(ws);           ws += 4096u * 4u;
  float* sumc  = (float*)(ws);           ws += 64u;

  // zero the accumulated buffers (cvec | yv | sumc are contiguous)
  hipMemsetAsync(cvec, 0, (size_t)M_TOT * 4u + 4096u * 4u + 64u, stream);

  const int LDSB_PROJ = 65536;
  hipFuncSetAttribute((const void*)proj_kernel,
                      hipFuncAttributeMaxDynamicSharedMemorySize, LDSB_PROJ);

  splitW_kernel<<<dim3(512), dim3(256), 0, stream>>>(W1, W2, WTh, WTl);
  proj_kernel<<<dim3(512), dim3(256), LDSB_PROJ, stream>>>(x, WTh, WTl, b1, b2, Qf, Kf);
  pass1_kernel<<<dim3(256), dim3(512), 32768, stream>>>(Qf, Kf, mpart, lpart);
  merge_kernel<<<dim3(128), dim3(256), 0, stream>>>(mpart, lpart, mfin, linv);
  pass2_kernel<<<dim3(256), dim3(512), 32768, stream>>>(Qf, Kf, mfin, linv, cvec);
  reducey_kernel<<<dim3(256), dim3(256), 0, stream>>>(x, cvec, yv, sumc);
  final_kernel<<<dim3(16), dim3(256), 0, stream>>>(yv, sumc, W3, b3, out);
}

// Round 6
// 229.473 us; speedup vs baseline: 1.8240x; 1.1305x over previous
//
#include <hip/hip_runtime.h>
#include <hip/hip_bf16.h>
#include <stdint.h>

typedef unsigned short u16;
typedef __attribute__((ext_vector_type(8)))  short    s16x8;
typedef __attribute__((ext_vector_type(8)))  _Float16 f16x8;
typedef __attribute__((ext_vector_type(16))) float    f32x16;

#define B_DIM 16
#define N_SEQ 2048
#define M_TOT (B_DIM * N_SEQ)   // 32768
#define LOG2E 1.44269504088896f
#define SHIFT 64.0f             // fixed softmax shift (log2 units)

static __device__ __forceinline__ f32x16 MFMA16(f16x8 a, f16x8 b, f32x16 c) {
  return __builtin_amdgcn_mfma_f32_32x32x16_f16(a, b, c, 0, 0, 0);
}

// Stage a 32-row x 512-B fp16 tile into LDS with involution swizzle
// (LDS(row, s) holds global (row, s ^ (row&7))). gload_lds dest is linear
// (uniform base + lane*16); the SOURCE address carries the swizzle. 256 thr.
static __device__ __forceinline__ void stage_f16(
    const u16* __restrict__ src, char* ldsbuf, int row0, int t)
{
#pragma unroll
  for (int jj = 0; jj < 4; ++jj) {
    const int row = (t >> 5) + jj * 8;           // 0..31 ; row&7 == t>>5
    const int sl  = (t & 31) ^ (t >> 5);         // swizzled 16B-slot
    const char* g = (const char*)src + ((size_t)(row0 + row) * 512 + (size_t)sl * 16);
    __builtin_amdgcn_global_load_lds(
        (const __attribute__((address_space(1))) uint32_t*)g,
        (__attribute__((address_space(3))) uint32_t*)(ldsbuf + t * 16 + jj * 4096),
        16, 0, 0);
  }
}

// XCD swizzle decode for 512-block grids: 64 sibling-groups x 8 members.
// Members of a group (same streamed working set) land on the same XCD.
#define SWZ8(bid, G_, J_)                                      \
  const int xcd_ = (bid) & 7, r_ = (bid) >> 3;                 \
  const int J_ = r_ & 7;                                       \
  const int G_ = ((r_ >> 3) << 3) | xcd_;

// ---------------------------------------------------------------------------
// W fold+transpose: WTf[a][k] fp16 (a<256: W1*log2e, else W2).
// ---------------------------------------------------------------------------
__global__ void splitW_kernel(const float* __restrict__ W1, const float* __restrict__ W2,
                              u16* __restrict__ WTf) {
  const int gid = blockIdx.x * 256 + threadIdx.x;   // 512 blocks
  const int a = gid >> 8, k = gid & 255;
  const float v = (a < 256) ? W1[k * 256 + a] * LOG2E : W2[k * 256 + (a - 256)];
  WTf[gid] = __builtin_bit_cast(u16, (_Float16)v);
}

// ---------------------------------------------------------------------------
// Projection: Qf = (x@W1+b1)*log2e, Kf = x@W2+b2, fp16 in and out.
// Single fp16 MFMA (error ~= fp16 storage rounding of Q/K themselves).
// ---------------------------------------------------------------------------
__global__ __launch_bounds__(256, 2) void proj_kernel(
    const float* __restrict__ x, const u16* __restrict__ WTf,
    const float* __restrict__ b1, const float* __restrict__ b2,
    u16* __restrict__ Qf, u16* __restrict__ Kf)
{
  __shared__ char lds[32768];   // 2 x 16 KB fp16 x-tiles
  const int t = threadIdx.x, wv = t >> 6, ln = t & 63, lr = ln & 31, g = ln >> 5;
  const int ablk = blockIdx.x & 3;
  const int m0 = (blockIdx.x >> 2) * 256;
  const int aglob = ablk * 128 + wv * 32 + lr;

  f16x8 wf[16];
  {
    const u16* base = WTf + (size_t)aglob * 256 + g * 8;
#pragma unroll
    for (int c = 0; c < 16; ++c) wf[c] = *(const f16x8*)(base + c * 16);
  }
  const float bias = (aglob < 256) ? b1[aglob] * LOG2E : b2[aglob - 256];
  u16* Of = (ablk < 2) ? Qf : Kf;
  const int acol = aglob & 255;

  const int srow = t >> 3;            // staging row 0..31
  const int scol = (t & 7) * 32;      // 32 f32 per thread

  float4 v[8];
  { // prologue: rows m0 -> fp16 -> swizzled buf0
    const float* src = x + (size_t)(m0 + srow) * 256 + scol;
#pragma unroll
    for (int j = 0; j < 8; ++j) v[j] = *(const float4*)(src + j * 4);
#pragma unroll
    for (int q8 = 0; q8 < 4; ++q8) {
      float ff[8] = {v[q8*2].x, v[q8*2].y, v[q8*2].z, v[q8*2].w,
                     v[q8*2+1].x, v[q8*2+1].y, v[q8*2+1].z, v[q8*2+1].w};
      f16x8 H;
#pragma unroll
      for (int e = 0; e < 8; ++e) H[e] = (_Float16)ff[e];
      const int swz = (((t & 7) * 4 + q8) ^ (srow & 7));
      *(f16x8*)(lds + srow * 512 + swz * 16) = H;
    }
  }
  __syncthreads();
  int p = 0;
  for (int it = 0; it < 8; ++it) {
    if (it + 1 < 8) {
      const float* src = x + (size_t)(m0 + (it + 1) * 32 + srow) * 256 + scol;
#pragma unroll
      for (int j = 0; j < 8; ++j) v[j] = *(const float4*)(src + j * 4);
    }
    const char* bh = lds + p * 16384;
    f32x16 S = {};
#pragma unroll
    for (int cc = 0; cc < 16; ++cc) {
      const int sl = ((cc * 2 + g) ^ (lr & 7)) * 16;
      const f16x8 a = *(const f16x8*)(bh + lr * 512 + sl);
      S = MFMA16(a, wf[cc], S);
    }
#pragma unroll
    for (int i = 0; i < 16; ++i) {
      const int mrow = m0 + it * 32 + (i & 3) + 8 * (i >> 2) + 4 * g;
      const float val = S[i] + bias;
      Of[(size_t)mrow * 256 + acol] = __builtin_bit_cast(u16, (_Float16)val);
    }
    if (it + 1 < 8) {
      char* bp = lds + (p ^ 1) * 16384;
#pragma unroll
      for (int q8 = 0; q8 < 4; ++q8) {
        float ff[8] = {v[q8*2].x, v[q8*2].y, v[q8*2].z, v[q8*2].w,
                       v[q8*2+1].x, v[q8*2+1].y, v[q8*2+1].z, v[q8*2+1].w};
        f16x8 H;
#pragma unroll
        for (int e = 0; e < 8; ++e) H[e] = (_Float16)ff[e];
        const int swz = (((t & 7) * 4 + q8) ^ (srow & 7));
        *(f16x8*)(bp + srow * 512 + swz * 16) = H;
      }
    }
    __syncthreads();
    p ^= 1;
  }
}

// ---------------------------------------------------------------------------
// Pass 1: l_q += sum_k exp2(S' - 64) over one key-quarter.
// Block = 4 waves x 64 q (Q in regs); K-quarter streamed via swizzled LDS.
// -SHIFT folded into the MFMA accumulator init. No max tracking.
// ---------------------------------------------------------------------------
__global__ __launch_bounds__(256, 2) void pass1_kernel(
    const u16* __restrict__ Qf, const u16* __restrict__ Kf,
    float* __restrict__ lsum)
{
  __shared__ char lds[32768];
  SWZ8(blockIdx.x, grp, qg);
  const int b = grp >> 2, kq = grp & 3;
  const int t = threadIdx.x, wv = t >> 6, ln = t & 63, lr = ln & 31, gg = ln >> 5;

  const int q0 = b * 2048 + qg * 256 + wv * 64;
  f16x8 qf0[16], qf1[16];
  {
    const u16* qb0 = Qf + (size_t)(q0 + lr) * 256 + gg * 8;
    const u16* qb1 = qb0 + 32 * 256;
#pragma unroll
    for (int c = 0; c < 16; ++c) {
      qf0[c] = *(const f16x8*)(qb0 + c * 16);
      qf1[c] = *(const f16x8*)(qb1 + c * 16);
    }
  }
  const int k0 = b * 2048 + kq * 512;

  stage_f16(Kf, lds, k0, t);
  __syncthreads();
  float l0 = 0.f, l1 = 0.f;
  int pp = 0;
  for (int it = 0; it < 16; ++it) {
    if (it + 1 < 16) stage_f16(Kf, lds + (pp ^ 1) * 16384, k0 + (it + 1) * 32, t);
    const char* bh = lds + pp * 16384;
    f32x16 S0, S1;
#pragma unroll
    for (int i = 0; i < 16; ++i) { S0[i] = -SHIFT; S1[i] = -SHIFT; }
#pragma unroll
    for (int c = 0; c < 16; ++c) {
      const int sl = ((c * 2 + gg) ^ (lr & 7)) * 16;
      const f16x8 a = *(const f16x8*)(bh + lr * 512 + sl);
      S0 = MFMA16(a, qf0[c], S0);
      S1 = MFMA16(a, qf1[c], S1);
    }
    float r0 = 0.f, r1 = 0.f;
#pragma unroll
    for (int i = 0; i < 16; ++i) { r0 += exp2f(S0[i]); r1 += exp2f(S1[i]); }
    l0 += r0; l1 += r1;
    __syncthreads();
    pp ^= 1;
  }
  l0 += __shfl_xor(l0, 32);
  l1 += __shfl_xor(l1, 32);
  if (ln < 32) {
    atomicAdd(&lsum[q0 + ln],      l0);
    atomicAdd(&lsum[q0 + 32 + ln], l1);
  }
}

// ---------------------------------------------------------------------------
// Pass 2: c_k += sum_q exp2(S' - 64) / l_q over one query-quarter.
// Block = 4 waves x 64 keys (K in regs); Q-quarter streamed via swizzled LDS.
// ---------------------------------------------------------------------------
__global__ __launch_bounds__(256, 2) void pass2_kernel(
    const u16* __restrict__ Qf, const u16* __restrict__ Kf,
    const float* __restrict__ lsum, float* __restrict__ cvec)
{
  __shared__ char lds[32768];
  SWZ8(blockIdx.x, grp, kg);
  const int b = grp >> 2, qq = grp & 3;
  const int t = threadIdx.x, wv = t >> 6, ln = t & 63, lr = ln & 31, gg = ln >> 5;

  const int k0 = b * 2048 + kg * 256 + wv * 64;
  f16x8 kf0[16], kf1[16];
  {
    const u16* kb0 = Kf + (size_t)(k0 + lr) * 256 + gg * 8;
    const u16* kb1 = kb0 + 32 * 256;
#pragma unroll
    for (int c = 0; c < 16; ++c) {
      kf0[c] = *(const f16x8*)(kb0 + c * 16);
      kf1[c] = *(const f16x8*)(kb1 + c * 16);
    }
  }
  const int q0 = b * 2048 + qq * 512;

  float ck0[16], ck1[16];
#pragma unroll
  for (int i = 0; i < 16; ++i) { ck0[i] = 0.f; ck1[i] = 0.f; }

  stage_f16(Qf, lds, q0, t);
  __syncthreads();
  int pp = 0;
  for (int it = 0; it < 16; ++it) {
    if (it + 1 < 16) stage_f16(Qf, lds + (pp ^ 1) * 16384, q0 + (it + 1) * 32, t);
    const float il = 1.0f / fmaxf(lsum[q0 + it * 32 + lr], 1e-30f);
    const char* bh = lds + pp * 16384;
    f32x16 S0, S1;
#pragma unroll
    for (int i = 0; i < 16; ++i) { S0[i] = -SHIFT; S1[i] = -SHIFT; }
#pragma unroll
    for (int c = 0; c < 16; ++c) {
      const int sl = ((c * 2 + gg) ^ (lr & 7)) * 16;
      const f16x8 qa = *(const f16x8*)(bh + lr * 512 + sl);
      S0 = MFMA16(kf0[c], qa, S0);
      S1 = MFMA16(kf1[c], qa, S1);
    }
#pragma unroll
    for (int i = 0; i < 16; ++i) {
      ck0[i] += exp2f(S0[i]) * il;
      ck1[i] += exp2f(S1[i]) * il;
    }
    __syncthreads();
    pp ^= 1;
  }
  // reduce over the 32 streamed q-columns (lanes within each gg half)
#pragma unroll
  for (int i = 0; i < 16; ++i) {
#pragma unroll
    for (int d = 1; d <= 16; d <<= 1) {
      ck0[i] += __shfl_xor(ck0[i], d);
      ck1[i] += __shfl_xor(ck1[i], d);
    }
  }
  if (lr == 0) {
#pragma unroll
    for (int i = 0; i < 16; ++i) {
      const int klocal = (i & 3) + 8 * (i >> 2) + 4 * gg;
      atomicAdd(&cvec[k0 + klocal],      ck0[i]);
      atomicAdd(&cvec[k0 + 32 + klocal], ck1[i]);
    }
  }
}

// y[b][d] = sum_k c_k x[b,k,d]; sumc[b] = sum_k c_k
__global__ void reducey_kernel(const float* __restrict__ x, const float* __restrict__ cvec,
                               float* __restrict__ yv, float* __restrict__ sumc) {
  const int b = blockIdx.x >> 4, kc = blockIdx.x & 15, tid = threadIdx.x;
  const float* xb = x + ((size_t)b * 2048 + kc * 128) * 256;
  const float* cb = cvec + b * 2048 + kc * 128;
  float a0 = 0.f, a1 = 0.f, a2 = 0.f, a3 = 0.f;
  for (int k = 0; k < 128; k += 4) {
    a0 = fmaf(cb[k],     xb[(size_t)k * 256 + tid],       a0);
    a1 = fmaf(cb[k + 1], xb[(size_t)(k + 1) * 256 + tid], a1);
    a2 = fmaf(cb[k + 2], xb[(size_t)(k + 2) * 256 + tid], a2);
    a3 = fmaf(cb[k + 3], xb[(size_t)(k + 3) * 256 + tid], a3);
  }
  atomicAdd(&yv[b * 256 + tid], (a0 + a1) + (a2 + a3));
  if (tid == 0) {
    float s = 0.f;
    for (int k = 0; k < 128; ++k) s += cb[k];
    atomicAdd(&sumc[b], s);
  }
}

// out[b][a] = sum_d y[b,d] W3[d,a] + sumc[b]*b3[a]
__global__ void final_kernel(const float* __restrict__ yv, const float* __restrict__ sumc,
                             const float* __restrict__ W3, const float* __restrict__ b3,
                             float* __restrict__ out) {
  __shared__ float ys[256];
  const int b = blockIdx.x, a = threadIdx.x;
  ys[a] = yv[b * 256 + a];
  __syncthreads();
  float acc = sumc[b] * b3[a];
#pragma unroll 4
  for (int d = 0; d < 256; ++d) acc = fmaf(ys[d], W3[d * 256 + a], acc);
  out[b * 256 + a] = acc;
}

// ---------------------------------------------------------------------------
extern "C" void kernel_launch(void* const* d_in, const int* in_sizes, int n_in,
                              void* d_out, int out_size, void* d_ws, size_t ws_size,
                              hipStream_t stream) {
  const float* x  = (const float*)d_in[0];
  const float* W1 = (const float*)d_in[1];
  const float* b1 = (const float*)d_in[2];
  const float* W2 = (const float*)d_in[3];
  const float* b2 = (const float*)d_in[4];
  const float* W3 = (const float*)d_in[5];
  const float* b3 = (const float*)d_in[6];
  float* out = (float*)d_out;

  char* ws = (char*)d_ws;
  const size_t SZ_WT = 512u * 256u * 2u;          // 262144 B
  const size_t SZ_QK = (size_t)M_TOT * 256u * 2u; // 16 MB
  u16* WTf = (u16*)(ws);                 ws += SZ_WT;
  u16* Qf  = (u16*)(ws);                 ws += SZ_QK;
  u16* Kf  = (u16*)(ws);                 ws += SZ_QK;
  float* lsum = (float*)(ws);            ws += (size_t)M_TOT * 4u;
  float* cvec = (float*)(ws);            ws += (size_t)M_TOT * 4u;
  float* yv   = (float*)(ws);            ws += 4096u * 4u;
  float* sumc = (float*)(ws);            ws += 64u;

  // zero the accumulated buffers (lsum | cvec | yv | sumc contiguous)
  hipMemsetAsync(lsum, 0, (size_t)M_TOT * 8u + 4096u * 4u + 64u, stream);

  splitW_kernel<<<dim3(512), dim3(256), 0, stream>>>(W1, W2, WTf);
  proj_kernel<<<dim3(512), dim3(256), 0, stream>>>(x, WTf, b1, b2, Qf, Kf);
  pass1_kernel<<<dim3(512), dim3(256), 0, stream>>>(Qf, Kf, lsum);
  pass2_kernel<<<dim3(512), dim3(256), 0, stream>>>(Qf, Kf, lsum, cvec);
  reducey_kernel<<<dim3(256), dim3(256), 0, stream>>>(x, cvec, yv, sumc);
  final_kernel<<<dim3(16), dim3(256), 0, stream>>>(yv, sumc, W3, b3, out);
}